// Round 1
// baseline (1027.560 us; speedup 1.0000x reference)
//
#include <hip/hip_runtime.h>

#define BATCH_N 20000

typedef __attribute__((ext_vector_type(4))) float  f32x4;
typedef __attribute__((ext_vector_type(8))) __bf16 bf16x8;
typedef __attribute__((ext_vector_type(8))) short  s16x8;
typedef __attribute__((ext_vector_type(8))) unsigned short u16x8;
typedef __attribute__((ext_vector_type(4))) unsigned short u16x4;
typedef unsigned short u16;
typedef unsigned int   u32;

// fp32 -> bf16, round-to-nearest-even
__device__ __forceinline__ u16 f2bf(float f) {
    union { float f; u32 u; } v; v.f = f;
    u32 r = v.u + 0x7fffu + ((v.u >> 16) & 1u);
    return (u16)(r >> 16);
}

// MFMA wrapper tolerant to either builtin operand typing (v8bf16 or v8i16).
template <typename C, typename V>
__device__ __forceinline__ auto mfma_bf16(V a, V b, C c, int)
    -> decltype(__builtin_amdgcn_mfma_f32_16x16x32_bf16(a, b, c, 0, 0, 0)) {
    return __builtin_amdgcn_mfma_f32_16x16x32_bf16(a, b, c, 0, 0, 0);
}
template <typename C, typename V>
__device__ __forceinline__ C mfma_bf16(V a, V b, C c, long) {
    return __builtin_amdgcn_mfma_f32_16x16x32_bf16(
        __builtin_bit_cast(s16x8, a), __builtin_bit_cast(s16x8, b), c, 0, 0, 0);
}

// 8 contiguous fp32 -> bf16x8 fragment
__device__ __forceinline__ bf16x8 cvt8(const float* p) {
    f32x4 v0 = *(const f32x4*)p;
    f32x4 v1 = *(const f32x4*)(p + 4);
    u16x8 raw = { f2bf(v0[0]), f2bf(v0[1]), f2bf(v0[2]), f2bf(v0[3]),
                  f2bf(v1[0]), f2bf(v1[1]), f2bf(v1[2]), f2bf(v1[3]) };
    return __builtin_bit_cast(bf16x8, raw);
}

template <typename WT>
__device__ __forceinline__ bf16x8 load_wfrag(const WT* p) {
    if constexpr (sizeof(WT) == 2) {
        return __builtin_bit_cast(bf16x8, *(const u16x8*)p);
    } else {
        return cvt8(p);
    }
}

// ---------------- l = 0 (d = 1): LDS-free path -----------------------------
// A = X rows (M = batch), B = W rows (B[k][o] = W[o][k]); D[row=batch][col=o].
template <typename WT>
__device__ __forceinline__ void run_l0(const float* __restrict__ x,
                                       const WT* __restrict__ W,
                                       const float* __restrict__ bias,
                                       float* __restrict__ out, int tile) {
    const int b0   = tile * 64;
    const int tid  = threadIdx.x;
    const int lane = tid & 63;
    const int wv   = tid >> 6;
    const int l15  = lane & 15;
    const int qd   = lane >> 4;

    f32x4 zero = {0.f, 0.f, 0.f, 0.f};
    f32x4 acc[4][4];
#pragma unroll
    for (int r = 0; r < 4; ++r)
#pragma unroll
        for (int c = 0; c < 4; ++c) acc[r][c] = zero;

    int brow[4];
#pragma unroll
    for (int r = 0; r < 4; ++r) {
        int b = b0 + r * 16 + l15;
        brow[r] = (b < BATCH_N) ? b : (BATCH_N - 1);  // clamp loads, guard stores
    }

#pragma unroll
    for (int kc = 0; kc < 4; ++kc) {
#pragma unroll
        for (int ks = 0; ks < 2; ++ks) {
            const int kg = kc * 64 + ks * 32 + qd * 8;
            bf16x8 a[4], bb[4];
#pragma unroll
            for (int r = 0; r < 4; ++r)
                a[r] = cvt8(x + (size_t)brow[r] * 4096 + kg);
#pragma unroll
            for (int c = 0; c < 4; ++c)
                bb[c] = load_wfrag(W + (size_t)(wv * 64 + c * 16 + l15) * 256 + kg);
#pragma unroll
            for (int r = 0; r < 4; ++r)
#pragma unroll
                for (int c = 0; c < 4; ++c)
                    acc[r][c] = mfma_bf16(a[r], bb[c], acc[r][c], 0);
        }
    }

    float bv[4];
#pragma unroll
    for (int c = 0; c < 4; ++c) bv[c] = bias[wv * 64 + c * 16 + l15];

#pragma unroll
    for (int r = 0; r < 4; ++r)
#pragma unroll
        for (int rg = 0; rg < 4; ++rg) {
            int b = b0 + r * 16 + qd * 4 + rg;
            if (b < BATCH_N) {
#pragma unroll
                for (int c = 0; c < 4; ++c)
                    out[(size_t)b * 4096 + wv * 64 + c * 16 + l15] = acc[r][c][rg] + bv[c];
            }
        }
}

// ---------------- generic l >= 1 path (d = 3,5,7) --------------------------
// A = W (global bf16 fragments), B = X via LDS transpose [col][k], pitch 72.
// Software-pipelined: chunk kc+1 is gathered into registers while chunk kc's
// MFMAs run, then written to the other LDS buffer. ONE barrier per kc:
//   lwrite_{k}(buf[(k+1)&1]) is separated from compute_{k-1}(buf[(k-1)&1]==
//   buf[(k+1)&1]) by barrier_k (WAR ok), and from compute_{k+1} by
//   barrier_{k+1} (RAW ok). No global load is outstanding at any barrier.
template <int D, int NB, int OFF, typename WT>
__device__ __forceinline__ void run_gen(const float* __restrict__ x,
                                        const WT* __restrict__ W,
                                        float* __restrict__ out,
                                        u16* xs, int tile) {
    constexpr int CM  = NB * D;              // max columns per block (<= 64)
    constexpr int NIT = CM * 16;             // staging work items per chunk
    constexpr int SUB = (NIT + 255) / 256;   // items per thread (== 4 here)
    constexpr int BUF = 64 * 72;             // u16 elements per LDS buffer
    const int b0   = tile * NB;
    const int nb   = (BATCH_N - b0 < NB) ? (BATCH_N - b0) : NB;
    const int cols = nb * D;
    const int tid  = threadIdx.x;
    const int lane = tid & 63;
    const int wv   = tid >> 6;
    const int l15  = lane & 15;
    const int qd   = lane >> 4;
    const int ob   = wv * 64;

    f32x4 zero = {0.f, 0.f, 0.f, 0.f};
    f32x4 acc[4][4];
#pragma unroll
    for (int r = 0; r < 4; ++r)
#pragma unroll
        for (int c = 0; c < 4; ++c) acc[r][c] = zero;

    u16x4 st[SUB];  // staged chunk held in registers (statically indexed)

    // gather chunk kc from global into st (strided 4B loads, bf16-converted)
    auto gload = [&](int kc) {
#pragma unroll
        for (int s = 0; s < SUB; ++s) {
            const int g = s * 256 + tid;
            if (g < NIT) {
                const int col = g % CM;          // compile-time magic div
                const int kq  = g / CM;          // 0..15
                if (col < cols) {
                    const int bq = col / D;
                    const int m  = col - bq * D;
                    const float* gp = x + (size_t)(b0 + bq) * 4096 + OFF +
                                      (kc * 64 + kq * 4) * D + m;
                    st[s] = (u16x4){ f2bf(gp[0]), f2bf(gp[D]),
                                     f2bf(gp[2 * D]), f2bf(gp[3 * D]) };
                }
            }
        }
    };
    // write staged registers into LDS buffer, transposed [col][k], pitch 72
    auto lwrite = [&](u16* buf) {
#pragma unroll
        for (int s = 0; s < SUB; ++s) {
            const int g = s * 256 + tid;
            if (g < NIT) {
                const int col = g % CM;
                const int kq  = g / CM;
                if (col < cols)
                    *(u16x4*)(buf + col * 72 + kq * 4) = st[s];
            }
        }
    };

    // prologue: chunk 0 (latency exposed once per block)
    gload(0);
    lwrite(xs);

#pragma unroll
    for (int kc = 0; kc < 4; ++kc) {
        u16* cur = xs + (kc & 1) * BUF;
        __syncthreads();                 // chunk kc visible; buf[(kc+1)&1] free
        if (kc < 3) gload(kc + 1);       // issue: in flight across the MFMAs

        // ---- compute chunk kc ----
#pragma unroll
        for (int ks = 0; ks < 2; ++ks) {
            const int kg = kc * 64 + ks * 32 + qd * 8;
            const int kl = ks * 32 + qd * 8;
            bf16x8 a[4], bb[4];
#pragma unroll
            for (int r = 0; r < 4; ++r)
                a[r] = load_wfrag(W + (size_t)(ob + r * 16 + l15) * 256 + kg);
#pragma unroll
            for (int c = 0; c < 4; ++c)
                bb[c] = __builtin_bit_cast(bf16x8,
                            *(const u16x8*)(cur + (c * 16 + l15) * 72 + kl));
#pragma unroll
            for (int r = 0; r < 4; ++r)
#pragma unroll
                for (int c = 0; c < 4; ++c)
                    acc[r][c] = mfma_bf16(a[r], bb[c], acc[r][c], 0);
        }

        if (kc < 3) lwrite(xs + ((kc + 1) & 1) * BUF);  // vmcnt waits land here
    }

    // ---- epilogue: D[row=o][col=(b,m)] -> out[b*4096 + OFF + o*D + m] ----
#pragma unroll
    for (int c = 0; c < 4; ++c) {
        int col = c * 16 + l15;
        if (col < cols) {
            int bq = col / D;
            int m  = col - bq * D;
            float* op = out + (size_t)(b0 + bq) * 4096 + OFF + m;
#pragma unroll
            for (int r = 0; r < 4; ++r)
#pragma unroll
                for (int rg = 0; rg < 4; ++rg) {
                    int o = ob + r * 16 + qd * 4 + rg;
                    op[o * D] = acc[r][c][rg];
                }
        }
    }
}

// ---------------- fused kernel ---------------------------------------------
// block ranges: l0 [0,313) l1 [313,1266) l2 [1266,2933) l3 [2933,5156)
// __launch_bounds__(256,5): cap VGPR at 102 so the +8 staging regs can't
// drop us from 5 to 4 waves/SIMD.
template <typename WT>
__global__ __launch_bounds__(256, 5) void so3_main(const float* __restrict__ x,
        const WT* __restrict__ W0, const WT* __restrict__ W1,
        const WT* __restrict__ W2, const WT* __restrict__ W3,
        const float* __restrict__ bias, float* __restrict__ out) {
    __shared__ __align__(16) u16 xs[2 * 64 * 72];   // double-buffered X tile
    int bid = blockIdx.x;
    if (bid < 313) {
        run_l0(x, W0, bias, out, bid);
    } else if (bid < 1266) {
        run_gen<3, 21, 256>(x, W1, out, xs, bid - 313);
    } else if (bid < 2933) {
        run_gen<5, 12, 1024>(x, W2, out, xs, bid - 1266);
    } else {
        run_gen<7, 9, 2304>(x, W3, out, xs, bid - 2933);
    }
}

// ---------------- W fp32 -> bf16 prologue ----------------------------------
__global__ __launch_bounds__(256) void w_to_bf16(const float* __restrict__ W0,
        const float* __restrict__ W1, const float* __restrict__ W2,
        const float* __restrict__ W3, u16* __restrict__ ws) {
    const float* Wt[4] = {W0, W1, W2, W3};
    const float* W = Wt[blockIdx.y];
    u16* o = ws + (size_t)blockIdx.y * 65536;
    int t = blockIdx.x * 256 + threadIdx.x;     // 0..16383 float4 groups
    f32x4 v = ((const f32x4*)W)[t];
    u16x4 u = { f2bf(v[0]), f2bf(v[1]), f2bf(v[2]), f2bf(v[3]) };
    ((u16x4*)o)[t] = u;
}

extern "C" void kernel_launch(void* const* d_in, const int* in_sizes, int n_in,
                              void* d_out, int out_size, void* d_ws, size_t ws_size,
                              hipStream_t stream) {
    const float* x    = (const float*)d_in[0];
    const float* W0   = (const float*)d_in[1];
    const float* W1   = (const float*)d_in[2];
    const float* W2   = (const float*)d_in[3];
    const float* W3   = (const float*)d_in[4];
    const float* bias = (const float*)d_in[5];
    float* out = (float*)d_out;

    if (ws_size >= 4ull * 65536ull * sizeof(u16)) {
        u16* wsW = (u16*)d_ws;
        w_to_bf16<<<dim3(64, 4), 256, 0, stream>>>(W0, W1, W2, W3, wsW);
        so3_main<u16><<<5156, 256, 0, stream>>>(x, wsW, wsW + 65536,
                                                wsW + 2 * 65536, wsW + 3 * 65536,
                                                bias, out);
    } else {
        // fallback: read fp32 W directly (converted per-fragment)
        so3_main<float><<<5156, 256, 0, stream>>>(x, W0, W1, W2, W3, bias, out);
    }
}

// Round 2
// 675.885 us; speedup vs baseline: 1.5203x; 1.5203x over previous
//
#include <hip/hip_runtime.h>

#define BATCH_N 20000

typedef __attribute__((ext_vector_type(4))) float  f32x4;
typedef __attribute__((ext_vector_type(8))) __bf16 bf16x8;
typedef __attribute__((ext_vector_type(8))) short  s16x8;
typedef __attribute__((ext_vector_type(8))) unsigned short u16x8;
typedef __attribute__((ext_vector_type(4))) unsigned short u16x4;
typedef unsigned short u16;
typedef unsigned int   u32;

// fp32 -> bf16, round-to-nearest-even
__device__ __forceinline__ u16 f2bf(float f) {
    union { float f; u32 u; } v; v.f = f;
    u32 r = v.u + 0x7fffu + ((v.u >> 16) & 1u);
    return (u16)(r >> 16);
}

// MFMA wrapper tolerant to either builtin operand typing (v8bf16 or v8i16).
template <typename C, typename V>
__device__ __forceinline__ auto mfma_bf16(V a, V b, C c, int)
    -> decltype(__builtin_amdgcn_mfma_f32_16x16x32_bf16(a, b, c, 0, 0, 0)) {
    return __builtin_amdgcn_mfma_f32_16x16x32_bf16(a, b, c, 0, 0, 0);
}
template <typename C, typename V>
__device__ __forceinline__ C mfma_bf16(V a, V b, C c, long) {
    return __builtin_amdgcn_mfma_f32_16x16x32_bf16(
        __builtin_bit_cast(s16x8, a), __builtin_bit_cast(s16x8, b), c, 0, 0, 0);
}

// 8 contiguous fp32 -> bf16x8 fragment
__device__ __forceinline__ bf16x8 cvt8(const float* p) {
    f32x4 v0 = *(const f32x4*)p;
    f32x4 v1 = *(const f32x4*)(p + 4);
    u16x8 raw = { f2bf(v0[0]), f2bf(v0[1]), f2bf(v0[2]), f2bf(v0[3]),
                  f2bf(v1[0]), f2bf(v1[1]), f2bf(v1[2]), f2bf(v1[3]) };
    return __builtin_bit_cast(bf16x8, raw);
}

template <typename WT>
__device__ __forceinline__ bf16x8 load_wfrag(const WT* p) {
    if constexpr (sizeof(WT) == 2) {
        return __builtin_bit_cast(bf16x8, *(const u16x8*)p);
    } else {
        return cvt8(p);
    }
}

// ---------------- l = 0 (d = 1): LDS-free path -----------------------------
// A = X rows (M = batch), B = W rows (B[k][o] = W[o][k]); D[row=batch][col=o].
template <typename WT>
__device__ __forceinline__ void run_l0(const float* __restrict__ x,
                                       const WT* __restrict__ W,
                                       const float* __restrict__ bias,
                                       float* __restrict__ out, int tile) {
    const int b0   = tile * 64;
    const int tid  = threadIdx.x;
    const int lane = tid & 63;
    const int wv   = tid >> 6;
    const int l15  = lane & 15;
    const int qd   = lane >> 4;

    f32x4 zero = {0.f, 0.f, 0.f, 0.f};
    f32x4 acc[4][4];
#pragma unroll
    for (int r = 0; r < 4; ++r)
#pragma unroll
        for (int c = 0; c < 4; ++c) acc[r][c] = zero;

    int brow[4];
#pragma unroll
    for (int r = 0; r < 4; ++r) {
        int b = b0 + r * 16 + l15;
        brow[r] = (b < BATCH_N) ? b : (BATCH_N - 1);  // clamp loads, guard stores
    }

#pragma unroll
    for (int kc = 0; kc < 4; ++kc) {
#pragma unroll
        for (int ks = 0; ks < 2; ++ks) {
            const int kg = kc * 64 + ks * 32 + qd * 8;
            bf16x8 a[4], bb[4];
#pragma unroll
            for (int r = 0; r < 4; ++r)
                a[r] = cvt8(x + (size_t)brow[r] * 4096 + kg);
#pragma unroll
            for (int c = 0; c < 4; ++c)
                bb[c] = load_wfrag(W + (size_t)(wv * 64 + c * 16 + l15) * 256 + kg);
#pragma unroll
            for (int r = 0; r < 4; ++r)
#pragma unroll
                for (int c = 0; c < 4; ++c)
                    acc[r][c] = mfma_bf16(a[r], bb[c], acc[r][c], 0);
        }
    }

    float bv[4];
#pragma unroll
    for (int c = 0; c < 4; ++c) bv[c] = bias[wv * 64 + c * 16 + l15];

#pragma unroll
    for (int r = 0; r < 4; ++r)
#pragma unroll
        for (int rg = 0; rg < 4; ++rg) {
            int b = b0 + r * 16 + qd * 4 + rg;
            if (b < BATCH_N) {
#pragma unroll
                for (int c = 0; c < 4; ++c)
                    out[(size_t)b * 4096 + wv * 64 + c * 16 + l15] = acc[r][c][rg] + bv[c];
            }
        }
}

// ---------------- generic l >= 1 path (d = 3,5,7) --------------------------
// A = W (global bf16 fragments), B = X via LDS transpose [col][k], pitch 72.
// Software-pipelined, double-buffered, ONE barrier per kc:
//   lwrite_{k}(buf[(k+1)&1]) is separated from compute_{k-1} (same buffer)
//   by barrier_k (WAR), and from compute_{k+1} by barrier_{k+1} (RAW).
// All staging address math is hoisted out of the kc loop; invalid work items
// load a clamped pointer and write into the row-pitch pad (bytes 64..67 of
// row 0, pitch 72) -- racy garbage into never-read pad, zero branches.
// NOTE: no min-waves launch bound. Round 1's __launch_bounds__(256,5)
// forced VGPR<=~96, spilled acc[4][4] to scratch (+1.4 GB HBM traffic, 2x
// slower). Let the allocator pick (~100 VGPR -> 5 waves/SIMD naturally).
template <int D, int NB, int OFF, typename WT>
__device__ __forceinline__ void run_gen(const float* __restrict__ x,
                                        const WT* __restrict__ W,
                                        float* __restrict__ out,
                                        u16* xs, int tile) {
    constexpr int CM  = NB * D;              // max columns per block (<= 64)
    constexpr int NIT = CM * 16;             // staging work items per chunk
    constexpr int BUF = 64 * 72;             // u16 elements per LDS buffer
    const int b0   = tile * NB;
    const int nb   = (BATCH_N - b0 < NB) ? (BATCH_N - b0) : NB;
    const int cols = nb * D;
    const int tid  = threadIdx.x;
    const int lane = tid & 63;
    const int wv   = tid >> 6;
    const int l15  = lane & 15;
    const int qd   = lane >> 4;
    const int ob   = wv * 64;

    f32x4 zero = {0.f, 0.f, 0.f, 0.f};
    f32x4 acc[4][4];
#pragma unroll
    for (int r = 0; r < 4; ++r)
#pragma unroll
        for (int c = 0; c < 4; ++c) acc[r][c] = zero;

    // ---- hoisted staging addresses (kc-invariant) ----
    const float* gp[4];   // global base for this work item (kc stride applied later)
    int          lo[4];   // LDS u16 offset
    u16x4        st[4];   // staged chunk in registers
#pragma unroll
    for (int s = 0; s < 4; ++s) {
        const int g   = s * 256 + tid;
        const int col = g % CM;              // compile-time magic div
        const int kq  = g / CM;              // 0..15
        const int bq  = col / D;
        const int m   = col - bq * D;
        const bool ok = (g < NIT) && (col < cols);
        gp[s] = ok ? (x + (size_t)(b0 + bq) * 4096 + OFF + (kq * 4) * D + m)
                   : x;                      // clamped safe read
        lo[s] = ok ? (col * 72 + kq * 4)
                   : 64;                     // pad bytes of row 0 (never read)
    }

#define GLOAD(kc_)                                                         \
    _Pragma("unroll")                                                      \
    for (int s = 0; s < 4; ++s) {                                          \
        const float* p = gp[s] + (kc_) * 64 * D;                           \
        st[s] = (u16x4){ f2bf(p[0]), f2bf(p[D]),                           \
                         f2bf(p[2 * D]), f2bf(p[3 * D]) };                 \
    }
#define LWRITE(buf_)                                                       \
    _Pragma("unroll")                                                      \
    for (int s = 0; s < 4; ++s)                                            \
        *(u16x4*)((buf_) + lo[s]) = st[s];

    // prologue: chunk 0 (latency exposed once per block)
    GLOAD(0);
    LWRITE(xs);

#pragma unroll
    for (int kc = 0; kc < 4; ++kc) {
        u16* cur = xs + (kc & 1) * BUF;
        __syncthreads();                 // chunk kc visible; buf[(kc+1)&1] free
        if (kc < 3) GLOAD(kc + 1);       // in flight across the MFMAs

        // ---- compute chunk kc ----
#pragma unroll
        for (int ks = 0; ks < 2; ++ks) {
            const int kg = kc * 64 + ks * 32 + qd * 8;
            const int kl = ks * 32 + qd * 8;
            bf16x8 a[4], bb[4];
#pragma unroll
            for (int r = 0; r < 4; ++r)
                a[r] = load_wfrag(W + (size_t)(ob + r * 16 + l15) * 256 + kg);
#pragma unroll
            for (int c = 0; c < 4; ++c)
                bb[c] = __builtin_bit_cast(bf16x8,
                            *(const u16x8*)(cur + (c * 16 + l15) * 72 + kl));
#pragma unroll
            for (int r = 0; r < 4; ++r)
#pragma unroll
                for (int c = 0; c < 4; ++c)
                    acc[r][c] = mfma_bf16(a[r], bb[c], acc[r][c], 0);
        }

        if (kc < 3) LWRITE(xs + ((kc + 1) & 1) * BUF);  // vmcnt waits land here
    }
#undef GLOAD
#undef LWRITE

    // ---- epilogue: D[row=o][col=(b,m)] -> out[b*4096 + OFF + o*D + m] ----
#pragma unroll
    for (int c = 0; c < 4; ++c) {
        int col = c * 16 + l15;
        if (col < cols) {
            int bq = col / D;
            int m  = col - bq * D;
            float* op = out + (size_t)(b0 + bq) * 4096 + OFF + m;
#pragma unroll
            for (int r = 0; r < 4; ++r)
#pragma unroll
                for (int rg = 0; rg < 4; ++rg) {
                    int o = ob + r * 16 + qd * 4 + rg;
                    op[o * D] = acc[r][c][rg];
                }
        }
    }
}

// ---------------- fused kernel ---------------------------------------------
// block ranges: l0 [0,313) l1 [313,1266) l2 [1266,2933) l3 [2933,5156)
template <typename WT>
__global__ __launch_bounds__(256) void so3_main(const float* __restrict__ x,
        const WT* __restrict__ W0, const WT* __restrict__ W1,
        const WT* __restrict__ W2, const WT* __restrict__ W3,
        const float* __restrict__ bias, float* __restrict__ out) {
    __shared__ __align__(16) u16 xs[2 * 64 * 72];   // double-buffered X tile
    int bid = blockIdx.x;
    if (bid < 313) {
        run_l0(x, W0, bias, out, bid);
    } else if (bid < 1266) {
        run_gen<3, 21, 256>(x, W1, out, xs, bid - 313);
    } else if (bid < 2933) {
        run_gen<5, 12, 1024>(x, W2, out, xs, bid - 1266);
    } else {
        run_gen<7, 9, 2304>(x, W3, out, xs, bid - 2933);
    }
}

// ---------------- W fp32 -> bf16 prologue ----------------------------------
__global__ __launch_bounds__(256) void w_to_bf16(const float* __restrict__ W0,
        const float* __restrict__ W1, const float* __restrict__ W2,
        const float* __restrict__ W3, u16* __restrict__ ws) {
    const float* Wt[4] = {W0, W1, W2, W3};
    const float* W = Wt[blockIdx.y];
    u16* o = ws + (size_t)blockIdx.y * 65536;
    int t = blockIdx.x * 256 + threadIdx.x;     // 0..16383 float4 groups
    f32x4 v = ((const f32x4*)W)[t];
    u16x4 u = { f2bf(v[0]), f2bf(v[1]), f2bf(v[2]), f2bf(v[3]) };
    ((u16x4*)o)[t] = u;
}

extern "C" void kernel_launch(void* const* d_in, const int* in_sizes, int n_in,
                              void* d_out, int out_size, void* d_ws, size_t ws_size,
                              hipStream_t stream) {
    const float* x    = (const float*)d_in[0];
    const float* W0   = (const float*)d_in[1];
    const float* W1   = (const float*)d_in[2];
    const float* W2   = (const float*)d_in[3];
    const float* W3   = (const float*)d_in[4];
    const float* bias = (const float*)d_in[5];
    float* out = (float*)d_out;

    if (ws_size >= 4ull * 65536ull * sizeof(u16)) {
        u16* wsW = (u16*)d_ws;
        w_to_bf16<<<dim3(64, 4), 256, 0, stream>>>(W0, W1, W2, W3, wsW);
        so3_main<u16><<<5156, 256, 0, stream>>>(x, wsW, wsW + 65536,
                                                wsW + 2 * 65536, wsW + 3 * 65536,
                                                bias, out);
    } else {
        // fallback: read fp32 W directly (converted per-fragment)
        so3_main<float><<<5156, 256, 0, stream>>>(x, W0, W1, W2, W3, bias, out);
    }
}